// Round 1
// baseline (559.672 us; speedup 1.0000x reference)
//
#include <hip/hip_runtime.h>

// ---------------------------------------------------------------------------
// MultiHeadAttention: B=4, S=2048, D=1024, H=16, dk=64
//   q = query@wq+bq; k = key@wk+bk; v = value@wv+bv   (fp32 in, bf16 compute)
//   att = softmax(q k^T / 8); o = att v; out = o@wo+bo (fp32 out)
// Precision plan: QKV projections in plain bf16 MFMA (errors suppressed by
// softmax averaging); final out-projection in split bf16 (hi+lo, 3 MFMA
// passes) to stay under the 6.25e-3 absmax threshold.
// ---------------------------------------------------------------------------

typedef __bf16 bf16;
typedef bf16  bf16x8 __attribute__((ext_vector_type(8)));
typedef bf16  bf16x4 __attribute__((ext_vector_type(4)));
typedef float f32x4  __attribute__((ext_vector_type(4)));

#define NROWS 8192     // B*S
#define DM    1024
#define SEQ   2048
#define DK    64

__device__ __forceinline__ f32x4 mfma16x16(bf16x8 a, bf16x8 b, f32x4 c) {
    return __builtin_amdgcn_mfma_f32_16x16x32_bf16(a, b, c, 0, 0, 0);
}

// ---- fp32 -> bf16 cast, 4 elements/thread --------------------------------
__global__ __launch_bounds__(256) void cast_bf16_kernel(
    const float* __restrict__ x, bf16* __restrict__ y, int n4) {
    int i = blockIdx.x * 256 + threadIdx.x;
    if (i >= n4) return;
    const float4 v = ((const float4*)x)[i];
    bf16x4 o;
    o[0] = (bf16)v.x; o[1] = (bf16)v.y; o[2] = (bf16)v.z; o[3] = (bf16)v.w;
    ((bf16x4*)y)[i] = o;
}

// ---- transpose 1024x1024 fp32 W[k][n] -> bf16 T[n][k] (+ optional lo) ----
template<bool SPLIT>
__global__ __launch_bounds__(256) void transpose_w_kernel(
    const float* __restrict__ W, bf16* __restrict__ Th, bf16* __restrict__ Tl) {
    __shared__ float tile[32][33];
    const int tx = threadIdx.x, ty = threadIdx.y;
    const int bx = blockIdx.x * 32, by = blockIdx.y * 32;
#pragma unroll
    for (int j = 0; j < 4; ++j)
        tile[ty + 8 * j][tx] = W[(size_t)(by + ty + 8 * j) * DM + bx + tx];
    __syncthreads();
#pragma unroll
    for (int j = 0; j < 4; ++j) {
        float v = tile[tx][ty + 8 * j];
        size_t o = (size_t)(bx + ty + 8 * j) * DM + by + tx;
        bf16 h = (bf16)v;
        Th[o] = h;
        if (SPLIT) Tl[o] = (bf16)(v - (float)h);
    }
}

// ---- GEMM: C[8192][1024] = A[8192][1024] @ Bt[1024][1024]^T + bias --------
// Bt is [n][k]. NSEG=1: plain bf16. NSEG=3: Ahi*Bhi + Ahi*Blo + Alo*Bhi.
// 128x128 block tile, 4 waves (2x2), each wave 64x64 = 4x4 MFMA frags.
template<int NSEG, bool OUTF32>
__global__ __launch_bounds__(256) void gemm_kernel(
    const bf16* __restrict__ Ahi, const bf16* __restrict__ Alo,
    const bf16* __restrict__ Bhi, const bf16* __restrict__ Blo,
    const float* __restrict__ bias, float oscale, void* __restrict__ outp) {
    const int tid = threadIdx.x;
    const int lane = tid & 63;
    const int w = tid >> 6;
    const int wr = w >> 1, wc = w & 1;
    const int li = lane & 15, lg = lane >> 4;
    const int m0 = blockIdx.y * 128, n0 = blockIdx.x * 128;

    __shared__ bf16 At[128 * 64];
    __shared__ bf16 Bt[128 * 64];

    f32x4 acc[4][4] = {};

    const bf16* Aseg[3] = { Ahi, Ahi, Alo };
    const bf16* Bseg[3] = { Bhi, Blo, Bhi };

#pragma unroll
    for (int seg = 0; seg < NSEG; ++seg) {
        const bf16* __restrict__ A = Aseg[seg];
        const bf16* __restrict__ B = Bseg[seg];
        for (int k0 = 0; k0 < DM; k0 += 64) {
            __syncthreads();
#pragma unroll
            for (int it = 0; it < 4; ++it) {
                int c = it * 256 + tid;
                int r = c >> 3, co = (c & 7) * 8;
                *(bf16x8*)&At[r * 64 + co] =
                    *(const bf16x8*)&A[(size_t)(m0 + r) * DM + k0 + co];
                *(bf16x8*)&Bt[r * 64 + co] =
                    *(const bf16x8*)&B[(size_t)(n0 + r) * DM + k0 + co];
            }
            __syncthreads();
            bf16x8 af[4][2], bfr[4][2];
#pragma unroll
            for (int mf = 0; mf < 4; ++mf)
#pragma unroll
                for (int ks = 0; ks < 2; ++ks)
                    af[mf][ks] = *(const bf16x8*)&At[(wr * 64 + mf * 16 + li) * 64 + ks * 32 + lg * 8];
#pragma unroll
            for (int nf = 0; nf < 4; ++nf)
#pragma unroll
                for (int ks = 0; ks < 2; ++ks)
                    bfr[nf][ks] = *(const bf16x8*)&Bt[(wc * 64 + nf * 16 + li) * 64 + ks * 32 + lg * 8];
#pragma unroll
            for (int ks = 0; ks < 2; ++ks)
#pragma unroll
                for (int mf = 0; mf < 4; ++mf)
#pragma unroll
                    for (int nf = 0; nf < 4; ++nf)
                        acc[mf][nf] = mfma16x16(af[mf][ks], bfr[nf][ks], acc[mf][nf]);
        }
    }
#pragma unroll
    for (int nf = 0; nf < 4; ++nf) {
        int col = n0 + wc * 64 + nf * 16 + li;
        float bv = bias[col];
#pragma unroll
        for (int mf = 0; mf < 4; ++mf) {
#pragma unroll
            for (int r = 0; r < 4; ++r) {
                int row = m0 + wr * 64 + mf * 16 + lg * 4 + r;
                float v = (acc[mf][nf][r] + bv) * oscale;
                if (OUTF32) ((float*)outp)[(size_t)row * DM + col] = v;
                else        ((bf16*)outp)[(size_t)row * DM + col] = (bf16)v;
            }
        }
    }
}

// ---- Flash attention: per block = one (b,h), 128 q rows; 4 waves x 32 rows.
// Qb already contains q/8 (scale folded into Q projection epilogue).
// Writes O as bf16 hi/lo pair for the split out-projection.
__global__ __launch_bounds__(256) void attn_kernel(
    const bf16* __restrict__ Qb, const bf16* __restrict__ Kb,
    const bf16* __restrict__ Vb,
    bf16* __restrict__ Ohi, bf16* __restrict__ Olo) {
    const int tid = threadIdx.x;
    const int lane = tid & 63;
    const int w = tid >> 6;
    const int li = lane & 15, lg = lane >> 4;
    const int qt = blockIdx.x;          // 0..15
    const int b  = blockIdx.y >> 4;     // 0..3
    const int h  = blockIdx.y & 15;     // 0..15
    const size_t rowQ = (size_t)b * SEQ + (size_t)qt * 128;
    const int c0 = h * DK;

    __shared__ bf16 Kt[64 * 64];        // [key][d]
    __shared__ bf16 Vt[64 * 64];        // [d][kv] (transposed)
    __shared__ bf16 Pl[4][32 * 64];     // per-wave P scratch

    // hoist Q fragments (A-operand layout: row=lane%16, k=(lane/16)*8+j)
    bf16x8 qf[2][2];
#pragma unroll
    for (int mf = 0; mf < 2; ++mf)
#pragma unroll
        for (int ks = 0; ks < 2; ++ks)
            qf[mf][ks] = *(const bf16x8*)&Qb[(rowQ + w * 32 + mf * 16 + li) * DM + c0 + ks * 32 + lg * 8];

    float mrow[2][4], lrow[2][4];
    f32x4 oacc[2][4] = {};
#pragma unroll
    for (int mf = 0; mf < 2; ++mf)
#pragma unroll
        for (int r = 0; r < 4; ++r) { mrow[mf][r] = -1e30f; lrow[mf][r] = 0.f; }

    for (int kt = 0; kt < SEQ / 64; ++kt) {
        const size_t rowK = (size_t)b * SEQ + (size_t)kt * 64;
        // stage K row-major and V transposed
#pragma unroll
        for (int it = 0; it < 2; ++it) {
            int c = it * 256 + tid;
            int kv = c >> 3, d0 = (c & 7) * 8;
            *(bf16x8*)&Kt[kv * 64 + d0] =
                *(const bf16x8*)&Kb[(rowK + kv) * DM + c0 + d0];
            bf16x8 vv = *(const bf16x8*)&Vb[(rowK + kv) * DM + c0 + d0];
#pragma unroll
            for (int j = 0; j < 8; ++j) Vt[(d0 + j) * 64 + kv] = vv[j];
        }
        __syncthreads();

        // S = Q K^T  (scale already folded into Q)
        f32x4 s[2][4] = {};
#pragma unroll
        for (int nf = 0; nf < 4; ++nf) {
            bf16x8 kf0 = *(const bf16x8*)&Kt[(nf * 16 + li) * 64 + 0 + lg * 8];
            bf16x8 kf1 = *(const bf16x8*)&Kt[(nf * 16 + li) * 64 + 32 + lg * 8];
#pragma unroll
            for (int mf = 0; mf < 2; ++mf) {
                s[mf][nf] = mfma16x16(qf[mf][0], kf0, s[mf][nf]);
                s[mf][nf] = mfma16x16(qf[mf][1], kf1, s[mf][nf]);
            }
        }

        // online softmax (rows: q = mf*16 + lg*4 + r; reduce over 16 lanes)
#pragma unroll
        for (int mf = 0; mf < 2; ++mf) {
            float rmax[4], rsum[4], cor[4];
#pragma unroll
            for (int r = 0; r < 4; ++r)
                rmax[r] = fmaxf(fmaxf(s[mf][0][r], s[mf][1][r]),
                                fmaxf(s[mf][2][r], s[mf][3][r]));
#pragma unroll
            for (int off = 1; off < 16; off <<= 1)
#pragma unroll
                for (int r = 0; r < 4; ++r)
                    rmax[r] = fmaxf(rmax[r], __shfl_xor(rmax[r], off));
#pragma unroll
            for (int r = 0; r < 4; ++r) {
                float mnew = fmaxf(mrow[mf][r], rmax[r]);
                cor[r] = __expf(mrow[mf][r] - mnew);
                mrow[mf][r] = mnew;
                rsum[r] = 0.f;
            }
#pragma unroll
            for (int nf = 0; nf < 4; ++nf)
#pragma unroll
                for (int r = 0; r < 4; ++r) {
                    float p = __expf(s[mf][nf][r] - mrow[mf][r]);
                    s[mf][nf][r] = p;
                    rsum[r] += p;
                }
#pragma unroll
            for (int off = 1; off < 16; off <<= 1)
#pragma unroll
                for (int r = 0; r < 4; ++r)
                    rsum[r] += __shfl_xor(rsum[r], off);
#pragma unroll
            for (int r = 0; r < 4; ++r)
                lrow[mf][r] = lrow[mf][r] * cor[r] + rsum[r];
#pragma unroll
            for (int nf = 0; nf < 4; ++nf)
#pragma unroll
                for (int r = 0; r < 4; ++r)
                    oacc[mf][nf][r] *= cor[r];
            // P -> LDS (D-layout write)
#pragma unroll
            for (int nf = 0; nf < 4; ++nf)
#pragma unroll
                for (int r = 0; r < 4; ++r)
                    Pl[w][(mf * 16 + lg * 4 + r) * 64 + nf * 16 + li] = (bf16)s[mf][nf][r];
        }
        __syncthreads();

        // O += P V   (A = P from LDS in A-layout, B = V from Vt)
        bf16x8 pf[2][2];
#pragma unroll
        for (int mf = 0; mf < 2; ++mf)
#pragma unroll
            for (int ks = 0; ks < 2; ++ks)
                pf[mf][ks] = *(const bf16x8*)&Pl[w][(mf * 16 + li) * 64 + ks * 32 + lg * 8];
#pragma unroll
        for (int nf = 0; nf < 4; ++nf) {
            bf16x8 vf0 = *(const bf16x8*)&Vt[(nf * 16 + li) * 64 + 0 + lg * 8];
            bf16x8 vf1 = *(const bf16x8*)&Vt[(nf * 16 + li) * 64 + 32 + lg * 8];
#pragma unroll
            for (int mf = 0; mf < 2; ++mf) {
                oacc[mf][nf] = mfma16x16(pf[mf][0], vf0, oacc[mf][nf]);
                oacc[mf][nf] = mfma16x16(pf[mf][1], vf1, oacc[mf][nf]);
            }
        }
        __syncthreads();
    }

    // epilogue: O /= l, write hi/lo bf16
#pragma unroll
    for (int mf = 0; mf < 2; ++mf)
#pragma unroll
        for (int nf = 0; nf < 4; ++nf)
#pragma unroll
            for (int r = 0; r < 4; ++r) {
                size_t row = rowQ + w * 32 + mf * 16 + lg * 4 + r;
                int col = c0 + nf * 16 + li;
                float v = oacc[mf][nf][r] / lrow[mf][r];
                bf16 hv = (bf16)v;
                Ohi[row * DM + col] = hv;
                Olo[row * DM + col] = (bf16)(v - (float)hv);
            }
}

// ---------------------------------------------------------------------------
extern "C" void kernel_launch(void* const* d_in, const int* in_sizes, int n_in,
                              void* d_out, int out_size, void* d_ws, size_t ws_size,
                              hipStream_t stream) {
    const float* query = (const float*)d_in[0];
    const float* key   = (const float*)d_in[1];
    const float* value = (const float*)d_in[2];
    const float* wq    = (const float*)d_in[3];
    const float* bq    = (const float*)d_in[4];
    const float* wk    = (const float*)d_in[5];
    const float* bk    = (const float*)d_in[6];
    const float* wv    = (const float*)d_in[7];
    const float* bv    = (const float*)d_in[8];
    const float* wo    = (const float*)d_in[9];
    const float* bo    = (const float*)d_in[10];

    char* ws = (char*)d_ws;
    const size_t SZX = (size_t)NROWS * DM * 2;   // 16 MB
    const size_t SZW = (size_t)DM * DM * 2;      //  2 MB
    bf16* Xb  = (bf16*)(ws);                     // input cast buffer (reused), later Ohi
    bf16* Wth = (bf16*)(ws + SZX);
    bf16* Wtl = (bf16*)(ws + SZX + SZW);
    bf16* Qb  = (bf16*)(ws + SZX + 2 * SZW);
    bf16* Kb  = (bf16*)(ws + 2 * SZX + 2 * SZW);
    bf16* Vb  = (bf16*)(ws + 3 * SZX + 2 * SZW);
    bf16* Olo = (bf16*)(ws + 4 * SZX + 2 * SZW);
    bf16* Ohi = Xb;                              // Xb is dead after V projection

    const dim3 bT(32, 8), gT(32, 32);
    const dim3 gemmG(8, 64);
    const int n4 = NROWS * DM / 4;

    // Q projection (scale 1/8 folded in)
    cast_bf16_kernel<<<8192, 256, 0, stream>>>(query, Xb, n4);
    transpose_w_kernel<false><<<gT, bT, 0, stream>>>(wq, Wth, nullptr);
    gemm_kernel<1, false><<<gemmG, 256, 0, stream>>>(Xb, nullptr, Wth, nullptr, bq, 0.125f, Qb);
    // K projection
    cast_bf16_kernel<<<8192, 256, 0, stream>>>(key, Xb, n4);
    transpose_w_kernel<false><<<gT, bT, 0, stream>>>(wk, Wth, nullptr);
    gemm_kernel<1, false><<<gemmG, 256, 0, stream>>>(Xb, nullptr, Wth, nullptr, bk, 1.0f, Kb);
    // V projection
    cast_bf16_kernel<<<8192, 256, 0, stream>>>(value, Xb, n4);
    transpose_w_kernel<false><<<gT, bT, 0, stream>>>(wv, Wth, nullptr);
    gemm_kernel<1, false><<<gemmG, 256, 0, stream>>>(Xb, nullptr, Wth, nullptr, bv, 1.0f, Vb);
    // attention
    attn_kernel<<<dim3(16, 64), 256, 0, stream>>>(Qb, Kb, Vb, Ohi, Olo);
    // output projection (split precision, fp32 out)
    transpose_w_kernel<true><<<gT, bT, 0, stream>>>(wo, Wth, Wtl);
    gemm_kernel<3, true><<<gemmG, 256, 0, stream>>>(Ohi, Olo, Wth, Wtl, bo, 1.0f, (float*)d_out);
}

// Round 2
// 303.086 us; speedup vs baseline: 1.8466x; 1.8466x over previous
//
#include <hip/hip_runtime.h>

// ---------------------------------------------------------------------------
// MultiHeadAttention: B=4, S=2048, D=1024, H=16, dk=64
// R2: swapped-QK^T flash attention (in-register softmax state, vectorized P),
//     XOR-swizzled LDS tiles everywhere, V^T produced by the V-proj epilogue,
//     reg-staged K/V prefetch, XCD-aware block swizzle, exp2 softmax,
//     defer-max rescale. Split-precision out-projection unchanged (passed R1).
// ---------------------------------------------------------------------------

typedef __bf16 bf16;
typedef bf16  bf16x8 __attribute__((ext_vector_type(8)));
typedef bf16  bf16x4 __attribute__((ext_vector_type(4)));
typedef float f32x4  __attribute__((ext_vector_type(4)));

#define NROWS 8192     // B*S
#define DM    1024
#define SEQ   2048
#define DK    64
#define LOG2E 1.44269504088896340736f

__device__ __forceinline__ f32x4 mfma16x16(bf16x8 a, bf16x8 b, f32x4 c) {
    return __builtin_amdgcn_mfma_f32_16x16x32_bf16(a, b, c, 0, 0, 0);
}

// ---- fp32 -> bf16 cast, 4 elements/thread --------------------------------
__global__ __launch_bounds__(256) void cast_bf16_kernel(
    const float* __restrict__ x, bf16* __restrict__ y, int n4) {
    int i = blockIdx.x * 256 + threadIdx.x;
    if (i >= n4) return;
    const float4 v = ((const float4*)x)[i];
    bf16x4 o;
    o[0] = (bf16)v.x; o[1] = (bf16)v.y; o[2] = (bf16)v.z; o[3] = (bf16)v.w;
    ((bf16x4*)y)[i] = o;
}

// ---- transpose 1024x1024 fp32 W[k][n] -> bf16 T[n][k] (+ optional lo) ----
template<bool SPLIT>
__global__ __launch_bounds__(256) void transpose_w_kernel(
    const float* __restrict__ W, bf16* __restrict__ Th, bf16* __restrict__ Tl) {
    __shared__ float tile[32][33];
    const int tx = threadIdx.x, ty = threadIdx.y;
    const int bx = blockIdx.x * 32, by = blockIdx.y * 32;
#pragma unroll
    for (int j = 0; j < 4; ++j)
        tile[ty + 8 * j][tx] = W[(size_t)(by + ty + 8 * j) * DM + bx + tx];
    __syncthreads();
#pragma unroll
    for (int j = 0; j < 4; ++j) {
        float v = tile[tx][ty + 8 * j];
        size_t o = (size_t)(bx + ty + 8 * j) * DM + by + tx;
        bf16 h = (bf16)v;
        Th[o] = h;
        if (SPLIT) Tl[o] = (bf16)(v - (float)h);
    }
}

// ---- GEMM: C[8192][1024] = A[8192][1024] @ Bt[1024][1024]^T + bias --------
// Bt is [n][k]. NSEG=1 plain bf16; NSEG=3 split (Ahi*Bhi+Ahi*Blo+Alo*Bhi).
// OUTMODE: 0 = bf16 row-major, 1 = f32 row-major, 2 = bf16 V^T ([b*1024+col][s])
template<int NSEG, int OUTMODE>
__global__ __launch_bounds__(256) void gemm_kernel(
    const bf16* __restrict__ Ahi, const bf16* __restrict__ Alo,
    const bf16* __restrict__ Bhi, const bf16* __restrict__ Blo,
    const float* __restrict__ bias, float oscale, void* __restrict__ outp) {
    const int tid = threadIdx.x;
    const int lane = tid & 63;
    const int w = tid >> 6;
    const int wr = w >> 1, wc = w & 1;
    const int li = lane & 15, lg = lane >> 4;
    const int m0 = blockIdx.y * 128, n0 = blockIdx.x * 128;

    __shared__ bf16 At[128 * 64];
    __shared__ bf16 Bt[128 * 64];

    f32x4 acc[4][4] = {};

    const bf16* Aseg[3] = { Ahi, Ahi, Alo };
    const bf16* Bseg[3] = { Bhi, Blo, Bhi };

#pragma unroll
    for (int seg = 0; seg < NSEG; ++seg) {
        const bf16* __restrict__ A = Aseg[seg];
        const bf16* __restrict__ B = Bseg[seg];
        for (int k0 = 0; k0 < DM; k0 += 64) {
            __syncthreads();
#pragma unroll
            for (int it = 0; it < 4; ++it) {
                int c = it * 256 + tid;
                int r = c >> 3, ch = c & 7, sl = ch ^ (r & 7);
                *(bf16x8*)&At[r * 64 + sl * 8] =
                    *(const bf16x8*)&A[(size_t)(m0 + r) * DM + k0 + ch * 8];
                *(bf16x8*)&Bt[r * 64 + sl * 8] =
                    *(const bf16x8*)&B[(size_t)(n0 + r) * DM + k0 + ch * 8];
            }
            __syncthreads();
            bf16x8 af[4][2], bfr[4][2];
#pragma unroll
            for (int mf = 0; mf < 4; ++mf)
#pragma unroll
                for (int ks = 0; ks < 2; ++ks)
                    af[mf][ks] = *(const bf16x8*)&At[(wr * 64 + mf * 16 + li) * 64 +
                                                     (((ks * 4 + lg) ^ (li & 7)) * 8)];
#pragma unroll
            for (int nf = 0; nf < 4; ++nf)
#pragma unroll
                for (int ks = 0; ks < 2; ++ks)
                    bfr[nf][ks] = *(const bf16x8*)&Bt[(wc * 64 + nf * 16 + li) * 64 +
                                                      (((ks * 4 + lg) ^ (li & 7)) * 8)];
#pragma unroll
            for (int ks = 0; ks < 2; ++ks)
#pragma unroll
                for (int mf = 0; mf < 4; ++mf)
#pragma unroll
                    for (int nf = 0; nf < 4; ++nf)
                        acc[mf][nf] = mfma16x16(af[mf][ks], bfr[nf][ks], acc[mf][nf]);
        }
    }
#pragma unroll
    for (int nf = 0; nf < 4; ++nf) {
        int col = n0 + wc * 64 + nf * 16 + li;
        float bv = bias[col];
        if (OUTMODE == 2) {
#pragma unroll
            for (int mf = 0; mf < 4; ++mf) {
                int rowb = m0 + wr * 64 + mf * 16 + lg * 4;
                bf16x4 pk;
#pragma unroll
                for (int r = 0; r < 4; ++r)
                    pk[r] = (bf16)((acc[mf][nf][r] + bv) * oscale);
                size_t o = ((size_t)(rowb >> 11) * 1024 + col) * SEQ + (rowb & 2047);
                *(bf16x4*)&((bf16*)outp)[o] = pk;
            }
        } else {
#pragma unroll
            for (int mf = 0; mf < 4; ++mf) {
#pragma unroll
                for (int r = 0; r < 4; ++r) {
                    int row = m0 + wr * 64 + mf * 16 + lg * 4 + r;
                    float v = (acc[mf][nf][r] + bv) * oscale;
                    if (OUTMODE == 1) ((float*)outp)[(size_t)row * DM + col] = v;
                    else              ((bf16*)outp)[(size_t)row * DM + col] = (bf16)v;
                }
            }
        }
    }
}

// ---- Flash attention, swapped QK^T ---------------------------------------
// Block = one (b,h) x 128 q rows; 4 waves x 32 q rows. KV tiles of 64.
// S^T = mfma(K, Q): lane holds q = li, kv = nf*16 + lg*4 + r  -> softmax
// state (m, l) is per-lane scalar per mf; P written to per-wave LDS as
// vectorized bf16x4; PV = mfma(P, V^T) -> O[q=lg*4+r][d=li].
__global__ __launch_bounds__(256) void attn_kernel(
    const bf16* __restrict__ Qb, const bf16* __restrict__ Kb,
    const bf16* __restrict__ Vtg,
    bf16* __restrict__ Ohi, bf16* __restrict__ Olo) {
    const int tid = threadIdx.x;
    const int lane = tid & 63;
    const int w = tid >> 6;
    const int li = lane & 15, lg = lane >> 4;

    // bijective XCD swizzle: 1024 blocks, XCD k owns bh in [k*8, k*8+8)
    int L = blockIdx.y * 16 + blockIdx.x;
    L = (L & 7) * 128 + (L >> 3);
    const int qt = L & 15, bh = L >> 4;
    const int b = bh >> 4, h = bh & 15;
    const size_t rowQ = (size_t)b * SEQ + (size_t)qt * 128;
    const int c0 = h * DK;

    __shared__ bf16 Kt[64 * 64];        // [kv][d], chunk-swizzled
    __shared__ bf16 Vt[64 * 64];        // [d][kv], chunk-swizzled
    __shared__ bf16 Pl[4][32 * 64];     // per-wave P [q][kv], chunk-swizzled

    // Q fragments (B-operand: q = li, k = d)
    bf16x8 qf[2][2];
#pragma unroll
    for (int mf = 0; mf < 2; ++mf)
#pragma unroll
        for (int ks = 0; ks < 2; ++ks)
            qf[mf][ks] = *(const bf16x8*)&Qb[(rowQ + w * 32 + mf * 16 + li) * DM +
                                             c0 + ks * 32 + lg * 8];

    float mrow[2] = { -1e30f, -1e30f };
    float lrow[2] = { 0.f, 0.f };
    f32x4 oacc[2][4] = {};

    const int sr = tid >> 3, sc = tid & 7;   // staging: row-base, chunk
    bf16x8 rk[2], rv[2];
    // prologue: issue tile 0 loads
#pragma unroll
    for (int it = 0; it < 2; ++it) {
        int r = it * 32 + sr;
        rk[it] = *(const bf16x8*)&Kb[((size_t)b * SEQ + r) * DM + c0 + sc * 8];
        rv[it] = *(const bf16x8*)&Vtg[((size_t)bh * 64 + r) * SEQ + sc * 8];
    }

    for (int kt = 0; kt < SEQ / 64; ++kt) {
        // write staged regs -> LDS (swizzled)
#pragma unroll
        for (int it = 0; it < 2; ++it) {
            int r = it * 32 + sr, sl = sc ^ (r & 7);
            *(bf16x8*)&Kt[r * 64 + sl * 8] = rk[it];
            *(bf16x8*)&Vt[r * 64 + sl * 8] = rv[it];
        }
        __syncthreads();
        if (kt + 1 < SEQ / 64) {        // prefetch next tile (overlaps compute)
#pragma unroll
            for (int it = 0; it < 2; ++it) {
                int r = it * 32 + sr;
                rk[it] = *(const bf16x8*)&Kb[((size_t)b * SEQ + (kt + 1) * 64 + r) * DM + c0 + sc * 8];
                rv[it] = *(const bf16x8*)&Vtg[((size_t)bh * 64 + r) * SEQ + (kt + 1) * 64 + sc * 8];
            }
        }

        // S^T = K Q^T : s[nf][mf], lane holds q=li, kv=nf*16+lg*4+r
        f32x4 s[4][2] = {};
#pragma unroll
        for (int nf = 0; nf < 4; ++nf)
#pragma unroll
            for (int ks = 0; ks < 2; ++ks) {
                bf16x8 kf = *(const bf16x8*)&Kt[(nf * 16 + li) * 64 +
                                                (((ks * 4 + lg) ^ (li & 7)) * 8)];
#pragma unroll
                for (int mf = 0; mf < 2; ++mf)
                    s[nf][mf] = mfma16x16(kf, qf[mf][ks], s[nf][mf]);
            }

        // online softmax (exp2 units; scale folded into Q projection)
        float rmax[2];
#pragma unroll
        for (int mf = 0; mf < 2; ++mf) {
            float m = s[0][mf][0];
#pragma unroll
            for (int nf = 0; nf < 4; ++nf)
#pragma unroll
                for (int r = 0; r < 4; ++r) m = fmaxf(m, s[nf][mf][r]);
            m = fmaxf(m, __shfl_xor(m, 16));
            m = fmaxf(m, __shfl_xor(m, 32));
            rmax[mf] = m;
        }
        bool need = (rmax[0] > mrow[0] + 12.f) || (rmax[1] > mrow[1] + 12.f);
        if (__any(need ? 1 : 0)) {
#pragma unroll
            for (int mf = 0; mf < 2; ++mf) {
                float mnew = fmaxf(mrow[mf], rmax[mf]);
                float cor = __builtin_amdgcn_exp2f(mrow[mf] - mnew);
                mrow[mf] = mnew;
                lrow[mf] *= cor;
#pragma unroll
                for (int r = 0; r < 4; ++r) {
                    float cb = __shfl(cor, lg * 4 + r);
#pragma unroll
                    for (int nf = 0; nf < 4; ++nf) oacc[mf][nf][r] *= cb;
                }
            }
        }
#pragma unroll
        for (int mf = 0; mf < 2; ++mf) {
            float rsum = 0.f;
            bf16x4 pk[4];
#pragma unroll
            for (int nf = 0; nf < 4; ++nf)
#pragma unroll
                for (int r = 0; r < 4; ++r) {
                    float p = __builtin_amdgcn_exp2f(s[nf][mf][r] - mrow[mf]);
                    rsum += p;
                    pk[nf][r] = (bf16)p;
                }
            rsum += __shfl_xor(rsum, 16);
            rsum += __shfl_xor(rsum, 32);
            lrow[mf] += rsum;
            // vectorized P write: row q = mf*16+li, cols nf*16+lg*4 .. +3
            int row = mf * 16 + li;
#pragma unroll
            for (int nf = 0; nf < 4; ++nf) {
                int sl = (nf * 2 + (lg >> 1)) ^ (li & 7);
                *(bf16x4*)&Pl[w][row * 64 + sl * 8 + (lg & 1) * 4] = pk[nf];
            }
        }

        // O += P V : A = P (row q=li), B = V^T (row d=li); out q=lg*4+r, d=li
#pragma unroll
        for (int ks = 0; ks < 2; ++ks) {
            bf16x8 pf[2];
#pragma unroll
            for (int mf = 0; mf < 2; ++mf)
                pf[mf] = *(const bf16x8*)&Pl[w][(mf * 16 + li) * 64 +
                                                (((ks * 4 + lg) ^ (li & 7)) * 8)];
#pragma unroll
            for (int nf = 0; nf < 4; ++nf) {
                bf16x8 vf = *(const bf16x8*)&Vt[(nf * 16 + li) * 64 +
                                                (((ks * 4 + lg) ^ (li & 7)) * 8)];
#pragma unroll
                for (int mf = 0; mf < 2; ++mf)
                    oacc[mf][nf] = mfma16x16(pf[mf], vf, oacc[mf][nf]);
            }
        }
        __syncthreads();
    }

    // epilogue: O /= l (broadcast from holder lanes), write hi/lo bf16
#pragma unroll
    for (int mf = 0; mf < 2; ++mf) {
        float rl = 1.0f / lrow[mf];
#pragma unroll
        for (int r = 0; r < 4; ++r) {
            float linv = __shfl(rl, lg * 4 + r);
            size_t row = rowQ + w * 32 + mf * 16 + lg * 4 + r;
#pragma unroll
            for (int nf = 0; nf < 4; ++nf) {
                int col = c0 + nf * 16 + li;
                float v = oacc[mf][nf][r] * linv;
                bf16 hv = (bf16)v;
                Ohi[row * DM + col] = hv;
                Olo[row * DM + col] = (bf16)(v - (float)hv);
            }
        }
    }
}

// ---------------------------------------------------------------------------
extern "C" void kernel_launch(void* const* d_in, const int* in_sizes, int n_in,
                              void* d_out, int out_size, void* d_ws, size_t ws_size,
                              hipStream_t stream) {
    const float* query = (const float*)d_in[0];
    const float* key   = (const float*)d_in[1];
    const float* value = (const float*)d_in[2];
    const float* wq    = (const float*)d_in[3];
    const float* bq    = (const float*)d_in[4];
    const float* wk    = (const float*)d_in[5];
    const float* bk    = (const float*)d_in[6];
    const float* wv    = (const float*)d_in[7];
    const float* bv    = (const float*)d_in[8];
    const float* wo    = (const float*)d_in[9];
    const float* bo    = (const float*)d_in[10];

    char* ws = (char*)d_ws;
    const size_t SZX = (size_t)NROWS * DM * 2;   // 16 MB
    const size_t SZW = (size_t)DM * DM * 2;      //  2 MB
    bf16* Xb  = (bf16*)(ws);                     // input cast buffer, later Ohi
    bf16* Wth = (bf16*)(ws + SZX);
    bf16* Wtl = (bf16*)(ws + SZX + SZW);
    bf16* Qb  = (bf16*)(ws + SZX + 2 * SZW);
    bf16* Kb  = (bf16*)(ws + 2 * SZX + 2 * SZW);
    bf16* Vtg = (bf16*)(ws + 3 * SZX + 2 * SZW); // V^T [b*1024+h*64+d][s]
    bf16* Olo = (bf16*)(ws + 4 * SZX + 2 * SZW);
    bf16* Ohi = Xb;                              // Xb dead after V projection

    const dim3 bT(32, 8), gT(32, 32);
    const dim3 gemmG(8, 64);
    const int n4 = NROWS * DM / 4;

    // Q projection (1/8 * log2e folded in -> softmax in exp2 units)
    cast_bf16_kernel<<<8192, 256, 0, stream>>>(query, Xb, n4);
    transpose_w_kernel<false><<<gT, bT, 0, stream>>>(wq, Wth, nullptr);
    gemm_kernel<1, 0><<<gemmG, 256, 0, stream>>>(Xb, nullptr, Wth, nullptr, bq, 0.125f * LOG2E, Qb);
    // K projection
    cast_bf16_kernel<<<8192, 256, 0, stream>>>(key, Xb, n4);
    transpose_w_kernel<false><<<gT, bT, 0, stream>>>(wk, Wth, nullptr);
    gemm_kernel<1, 0><<<gemmG, 256, 0, stream>>>(Xb, nullptr, Wth, nullptr, bk, 1.0f, Kb);
    // V projection -> V^T directly
    cast_bf16_kernel<<<8192, 256, 0, stream>>>(value, Xb, n4);
    transpose_w_kernel<false><<<gT, bT, 0, stream>>>(wv, Wth, nullptr);
    gemm_kernel<1, 2><<<gemmG, 256, 0, stream>>>(Xb, nullptr, Wth, nullptr, bv, 1.0f, Vtg);
    // attention
    attn_kernel<<<dim3(16, 64), 256, 0, stream>>>(Qb, Kb, Vtg, Ohi, Olo);
    // output projection (split precision, fp32 out)
    transpose_w_kernel<true><<<gT, bT, 0, stream>>>(wo, Wth, Wtl);
    gemm_kernel<3, 1><<<gemmG, 256, 0, stream>>>(Ohi, Olo, Wth, Wtl, bo, 1.0f, (float*)d_out);
}